// Round 10
// baseline (1970.336 us; speedup 1.0000x reference)
//
#include <hip/hip_runtime.h>

// ---------- bf16 helpers (bit-level, RNE) ----------
__device__ __forceinline__ float bf2f(unsigned short u) {
    union { unsigned int i; float f; } v;
    v.i = ((unsigned int)u) << 16;
    return v.f;
}
__device__ __forceinline__ unsigned short f2bf(float f) {
    union { float f; unsigned int u; } v;
    v.f = f;
    unsigned int u = v.u;
    u += 0x7FFFu + ((u >> 16) & 1u);   // round-to-nearest-even
    return (unsigned short)(u >> 16);
}
__device__ __forceinline__ float loadElem(const void* p, size_t i, int isb) {
    return isb ? bf2f(((const unsigned short*)p)[i]) : ((const float*)p)[i];
}
__device__ __forceinline__ void fma4(float4& a, float s, const float4& w) {
    a.x += s * w.x; a.y += s * w.y; a.z += s * w.z; a.w += s * w.w;
}
__device__ __forceinline__ void unpack8(uint4 u, float* v) {
    v[0] = bf2f((unsigned short)(u.x & 0xFFFF)); v[1] = bf2f((unsigned short)(u.x >> 16));
    v[2] = bf2f((unsigned short)(u.y & 0xFFFF)); v[3] = bf2f((unsigned short)(u.y >> 16));
    v[4] = bf2f((unsigned short)(u.z & 0xFFFF)); v[5] = bf2f((unsigned short)(u.z >> 16));
    v[6] = bf2f((unsigned short)(u.w & 0xFFFF)); v[7] = bf2f((unsigned short)(u.w >> 16));
}
__device__ __forceinline__ float bflo(unsigned int u) {
    union { unsigned int i; float f; } v; v.i = u << 16; return v.f;
}
__device__ __forceinline__ float bfhi(unsigned int u) {
    union { unsigned int i; float f; } v; v.i = u & 0xFFFF0000u; return v.f;
}
// pick bf16 element kk (0..7) from two uint2 (8 packed bf16); kk is compile-time
__device__ __forceinline__ float pick8(const uint2& A, const uint2& B, int kk) {
    unsigned int d = (kk < 4) ? ((kk & 2) ? A.y : A.x) : ((kk & 2) ? B.y : B.x);
    return (kk & 1) ? bfhi(d) : bflo(d);
}

#define CHUNK 2048            // edges per partition block (2.3 blocks/CU balance)
#define BSHIFT 8              // 256 nodes per sort bucket (r7 proven)

// ---------- runtime dtype detection (proven r3-r9) ----------
__global__ void k_detect(const int* __restrict__ ei, int newords,
                         const unsigned int* __restrict__ xw, int nxw,
                         int* __restrict__ flags) {
    __shared__ int aOr;
    __shared__ int plaus;
    if (threadIdx.x == 0) { aOr = 0; plaus = 0; }
    __syncthreads();
    int v = 0;
    for (int i = 1 + 2 * (int)threadIdx.x; i < newords; i += 512) v |= ei[i];
    int pl = 0;
    for (int i = threadIdx.x; i < nxw; i += 256) {
        unsigned short lo = (unsigned short)(xw[i] & 0xFFFFu);
        float a = fabsf(bf2f(lo));
        if (a > 1e-5f && a < 100.0f) pl++;
    }
    atomicOr(&aOr, v);
    atomicAdd(&plaus, pl);
    __syncthreads();
    if (threadIdx.x == 0) {
        flags[0] = (aOr == 0) ? 1 : 0;
        flags[1] = (2 * plaus >= nxw) ? 1 : 0;
    }
}

// ---------- cast x -> bf16 (copy-through if already bf16) ----------
__global__ void k_cast(const void* __restrict__ x, unsigned short* __restrict__ xb,
                       int n8, const int* __restrict__ flags) {
    int i = blockIdx.x * blockDim.x + threadIdx.x;
    if (i >= n8) return;
    if (flags[1]) {
        ((uint4*)xb)[i] = ((const uint4*)x)[i];
    } else {
        const float4* xf = (const float4*)x;
        float4 a = xf[2 * i], b = xf[2 * i + 1];
        ushort4 lo = { f2bf(a.x), f2bf(a.y), f2bf(a.z), f2bf(a.w) };
        ushort4 hi = { f2bf(b.x), f2bf(b.y), f2bf(b.z), f2bf(b.w) };
        ((ushort4*)xb)[2 * i] = lo;
        ((ushort4*)xb)[2 * i + 1] = hi;
    }
}

// ---------- CSR build: counting sort with parallel scans (r7/r9 proven) ----------
__global__ __launch_bounds__(256) void k_bcount(
        const int* __restrict__ ei, const int* __restrict__ flags,
        int* __restrict__ blockHist, int E, int NBUK, int nblk) {
    __shared__ int hist[512];
    int t = threadIdx.x;
    for (int i = t; i < NBUK; i += 256) hist[i] = 0;
    __syncthreads();
    int q = flags[0];
    int e0 = blockIdx.x * CHUNK, e1 = min(E, e0 + CHUNK);
    for (int e = e0 + t; e < e1; e += 256) {
        int dst = ei[((size_t)(E + e)) << q];
        atomicAdd(&hist[dst >> BSHIFT], 1);
    }
    __syncthreads();
    for (int i = t; i < NBUK; i += 256)
        blockHist[(size_t)i * nblk + blockIdx.x] = hist[i];
}

__global__ __launch_bounds__(256) void k_rowscan(
        int* __restrict__ blockHist, int* __restrict__ bukTot, int nblk) {
    __shared__ int sh[256];
    int t = threadIdx.x;
    int* row = blockHist + (size_t)blockIdx.x * nblk;
    int carry = 0;
    for (int base = 0; base < nblk; base += 256) {
        int i = base + t;
        int v = (i < nblk) ? row[i] : 0;
        sh[t] = v;
        __syncthreads();
        for (int off = 1; off < 256; off <<= 1) {
            int u = (t >= off) ? sh[t - off] : 0;
            __syncthreads();
            sh[t] += u;
            __syncthreads();
        }
        if (i < nblk) row[i] = carry + sh[t] - v;
        int tot = sh[255];
        __syncthreads();
        carry += tot;
    }
    if (t == 0) bukTot[blockIdx.x] = carry;
}

__global__ __launch_bounds__(512) void k_toto(
        const int* __restrict__ bukTot, int* __restrict__ bukOff,
        int* __restrict__ rowptr, int NBUK, int E, int N) {
    __shared__ int sh[512];
    int t = threadIdx.x;
    int v = (t < NBUK) ? bukTot[t] : 0;
    sh[t] = v;
    __syncthreads();
    for (int off = 1; off < 512; off <<= 1) {
        int u = (t >= off) ? sh[t - off] : 0;
        __syncthreads();
        sh[t] += u;
        __syncthreads();
    }
    if (t < NBUK) bukOff[t] = sh[t] - v;
    if (t == 0) { bukOff[NBUK] = E; rowptr[N] = E; }
}

__global__ __launch_bounds__(256) void k_part(
        const int* __restrict__ ei, const int* __restrict__ flags,
        const int* __restrict__ blockHist, const int* __restrict__ bukOff,
        unsigned int* __restrict__ recs, int E, int NBUK, int nblk) {
    __shared__ int cur[512];
    int t = threadIdx.x;
    for (int i = t; i < NBUK; i += 256)
        cur[i] = blockHist[(size_t)i * nblk + blockIdx.x] + bukOff[i];
    __syncthreads();
    int q = flags[0];
    int e0 = blockIdx.x * CHUNK, e1 = min(E, e0 + CHUNK);
    for (int e = e0 + t; e < e1; e += 256) {
        int dst = ei[((size_t)(E + e)) << q];
        int src = ei[((size_t)e) << q];
        int pos = atomicAdd(&cur[dst >> BSHIFT], 1);
        recs[pos] = ((unsigned int)src << BSHIFT) | (unsigned int)(dst & ((1 << BSHIFT) - 1));
    }
}

__global__ __launch_bounds__(256) void k_csr(
        const unsigned int* __restrict__ recs, const int* __restrict__ bukOff,
        int* __restrict__ rowptr, int* __restrict__ esorted, int N) {
    __shared__ int degLoc[256];
    __shared__ int offLoc[256];
    __shared__ int wcur[256];
    int t = threadIdx.x;
    int node0 = blockIdx.x << BSHIFT;
    int r0 = bukOff[blockIdx.x], r1 = bukOff[blockIdx.x + 1];
    degLoc[t] = 0;
    __syncthreads();
    for (int i = r0 + t; i < r1; i += 256)
        atomicAdd(&degLoc[recs[i] & 255], 1);
    __syncthreads();
    int v = degLoc[t];
    offLoc[t] = v;
    __syncthreads();
    for (int off = 1; off < 256; off <<= 1) {
        int u = (t >= off) ? offLoc[t - off] : 0;
        __syncthreads();
        offLoc[t] += u;
        __syncthreads();
    }
    int excl = offLoc[t] - v;
    int node = node0 + t;
    if (node < N) rowptr[node] = r0 + excl;
    wcur[t] = r0 + excl;
    __syncthreads();
    for (int i = r0 + t; i < r1; i += 256) {
        unsigned int rec = recs[i];
        int pos = atomicAdd(&wcur[rec & 255], 1);
        esorted[pos] = (int)(rec >> BSHIFT);
    }
}

// ---------- fused layer: CSR register-gather + double GEMM, occupancy-tuned ----------
// 128-node tile, 512 threads, bf16 LDS A-buffer (am16, stride 68 ushort):
//   phase 1: 16-lane groups gather mean_nbr(feat) in f32 regs -> bf16 am16
//   phase 2: acc  = am16 @ Wl (wS f32)
//   restage: own rows raw-copied into am16 (bit copy, no unpack); Wr -> wS
//   phase 3: acc += am16 @ Wr; epilogue +bias (+relu), store
// LDS = 17.4K (am16) + CHOUT*256 (wS) + CHOUT*4 -> 34K @ CHOUT=64 => 4 blk x 8 waves/CU
template<int CHOUT, bool RELU, bool FINAL>
__global__ __launch_bounds__(512) void k_fused(
        const unsigned short* __restrict__ feat,   // [N,64] bf16: xb (L1) or h (L2)
        const int* __restrict__ rowptr,
        const int* __restrict__ esorted,
        const void* __restrict__ Wl,               // [64,CHOUT]
        const void* __restrict__ Wr,               // [64,CHOUT]
        const void* __restrict__ bias,             // [CHOUT]
        void* __restrict__ outp,                   // [N,CHOUT]
        int N, const int* __restrict__ flags) {
    constexpr int S = 68;                          // ushort stride (8B-aligned rows)
    constexpr int BLKN = 128;
    __shared__ unsigned short am16[BLKN * S];
    __shared__ float wS[64 * CHOUT];
    __shared__ float Bs[CHOUT];

    int t = threadIdx.x;
    int isb = flags[1];
    int node0 = blockIdx.x * BLKN;

    // stage Wl
    if (isb) {
        for (int i = t; i < (64 * CHOUT) / 8; i += 512) {
            uint4 u = *(const uint4*)((const unsigned short*)Wl + (size_t)i * 8);
            float v[8]; unpack8(u, v);
#pragma unroll
            for (int j = 0; j < 8; ++j) wS[i * 8 + j] = v[j];
        }
    } else {
        for (int i = t; i < 64 * CHOUT; i += 512) wS[i] = ((const float*)Wl)[i];
    }
    if (t < CHOUT) Bs[t] = loadElem(bias, t, isb);

    // ---- phase 1: gather mean of neighbor rows -> am16 (bf16) ----
    {
        int g = t >> 4, l = t & 15;                // 32 groups of 16 lanes
        int gb = (t & 63) & ~15;                   // group base lane within wave
#pragma unroll
        for (int jj = 0; jj < 4; ++jj) {
            int nl = g + 32 * jj;
            int node = node0 + nl;
            float ax = 0.f, ay = 0.f, az = 0.f, aw = 0.f;
            float inv = 0.f;
            if (node < N) {
                int beg = rowptr[node], end = rowptr[node + 1];
                int d = end - beg;
                if (d > 0) {
                    inv = 1.0f / (float)d;
                    for (int bs = beg; bs < end; bs += 16) {
                        int cnt = min(end - bs, 16);
                        int idx = esorted[min(bs + l, end - 1)];
                        int dd = 0;
                        for (; dd + 4 <= cnt; dd += 4) {
                            int s0 = __shfl(idx, gb + dd + 0, 64);
                            int s1 = __shfl(idx, gb + dd + 1, 64);
                            int s2 = __shfl(idx, gb + dd + 2, 64);
                            int s3 = __shfl(idx, gb + dd + 3, 64);
                            ushort4 u0 = *(const ushort4*)(feat + (size_t)s0 * 64 + 4 * l);
                            ushort4 u1 = *(const ushort4*)(feat + (size_t)s1 * 64 + 4 * l);
                            ushort4 u2 = *(const ushort4*)(feat + (size_t)s2 * 64 + 4 * l);
                            ushort4 u3 = *(const ushort4*)(feat + (size_t)s3 * 64 + 4 * l);
                            ax += bf2f(u0.x) + bf2f(u1.x) + bf2f(u2.x) + bf2f(u3.x);
                            ay += bf2f(u0.y) + bf2f(u1.y) + bf2f(u2.y) + bf2f(u3.y);
                            az += bf2f(u0.z) + bf2f(u1.z) + bf2f(u2.z) + bf2f(u3.z);
                            aw += bf2f(u0.w) + bf2f(u1.w) + bf2f(u2.w) + bf2f(u3.w);
                        }
                        for (; dd < cnt; ++dd) {
                            int s = __shfl(idx, gb + dd, 64);
                            ushort4 u = *(const ushort4*)(feat + (size_t)s * 64 + 4 * l);
                            ax += bf2f(u.x); ay += bf2f(u.y);
                            az += bf2f(u.z); aw += bf2f(u.w);
                        }
                    }
                }
            }
            ushort4 o = { f2bf(ax * inv), f2bf(ay * inv), f2bf(az * inv), f2bf(aw * inv) };
            *(ushort4*)&am16[nl * S + 4 * l] = o;   // 8B-aligned
        }
    }
    __syncthreads();

    // ---- phase 2: acc = am @ Wl ----
    constexpr int CQ = CHOUT / 4;                  // 16 or 8
    constexpr int NPT = CHOUT / 16;                // 4 or 2 nodes per thread
    int cq = t % CQ, nq = t / CQ;                  // nq in [0, 128/NPT)
    float4 acc[NPT];
#pragma unroll
    for (int j = 0; j < NPT; ++j) acc[j] = make_float4(0.f, 0.f, 0.f, 0.f);

#pragma unroll
    for (int k0 = 0; k0 < 64; k0 += 8) {
        uint2 aA[NPT], aB[NPT];
#pragma unroll
        for (int j = 0; j < NPT; ++j) {
            const unsigned short* rp = &am16[(nq * NPT + j) * S + k0];
            aA[j] = *(const uint2*)rp;
            aB[j] = *(const uint2*)(rp + 4);
        }
#pragma unroll
        for (int kk = 0; kk < 8; ++kk) {
            float4 w = *(const float4*)&wS[(k0 + kk) * CHOUT + 4 * cq];
#pragma unroll
            for (int j = 0; j < NPT; ++j)
                fma4(acc[j], pick8(aA[j], aB[j], kk), w);
        }
    }
    __syncthreads();

    // ---- restage: own rows (raw bf16 copy) -> am16, Wr -> wS ----
    for (int i = t; i < BLKN * 8; i += 512) {
        int nl = i >> 3, k0 = (i & 7) << 3;
        int gn = node0 + nl;
        uint4 u = make_uint4(0, 0, 0, 0);
        if (gn < N) u = *(const uint4*)(feat + (size_t)gn * 64 + k0);
        *(uint2*)&am16[nl * S + k0]     = make_uint2(u.x, u.y);
        *(uint2*)&am16[nl * S + k0 + 4] = make_uint2(u.z, u.w);
    }
    if (isb) {
        for (int i = t; i < (64 * CHOUT) / 8; i += 512) {
            uint4 u = *(const uint4*)((const unsigned short*)Wr + (size_t)i * 8);
            float v[8]; unpack8(u, v);
#pragma unroll
            for (int j = 0; j < 8; ++j) wS[i * 8 + j] = v[j];
        }
    } else {
        for (int i = t; i < 64 * CHOUT; i += 512) wS[i] = ((const float*)Wr)[i];
    }
    __syncthreads();

    // ---- phase 3: acc += own @ Wr ----
#pragma unroll
    for (int k0 = 0; k0 < 64; k0 += 8) {
        uint2 aA[NPT], aB[NPT];
#pragma unroll
        for (int j = 0; j < NPT; ++j) {
            const unsigned short* rp = &am16[(nq * NPT + j) * S + k0];
            aA[j] = *(const uint2*)rp;
            aB[j] = *(const uint2*)(rp + 4);
        }
#pragma unroll
        for (int kk = 0; kk < 8; ++kk) {
            float4 w = *(const float4*)&wS[(k0 + kk) * CHOUT + 4 * cq];
#pragma unroll
            for (int j = 0; j < NPT; ++j)
                fma4(acc[j], pick8(aA[j], aB[j], kk), w);
        }
    }

    // ---- epilogue ----
    float4 bv = *(const float4*)&Bs[4 * cq];
#pragma unroll
    for (int j = 0; j < NPT; ++j) {
        int node = node0 + nq * NPT + j;
        if (node >= N) continue;
        float4 r = acc[j];
        r.x += bv.x; r.y += bv.y; r.z += bv.z; r.w += bv.w;
        if (RELU) {
            r.x = fmaxf(r.x, 0.f); r.y = fmaxf(r.y, 0.f);
            r.z = fmaxf(r.z, 0.f); r.w = fmaxf(r.w, 0.f);
        }
        if (FINAL && !isb) {
            *(float4*)((float*)outp + (size_t)node * CHOUT + 4 * cq) = r;
        } else {
            ushort4 o = { f2bf(r.x), f2bf(r.y), f2bf(r.z), f2bf(r.w) };
            *(ushort4*)((unsigned short*)outp + (size_t)node * CHOUT + 4 * cq) = o;
        }
    }
}

extern "C" void kernel_launch(void* const* d_in, const int* in_sizes, int n_in,
                              void* d_out, int out_size, void* d_ws, size_t ws_size,
                              hipStream_t stream) {
    const void* x   = d_in[0];
    const int*  ei  = (const int*)d_in[1];
    const void* W1l = d_in[2];
    const void* W1r = d_in[3];
    const void* b1  = d_in[4];
    const void* W2l = d_in[5];
    const void* W2r = d_in[6];
    const void* b2  = d_in[7];

    const int N = in_sizes[0] / 64;
    const int E = in_sizes[1] / 2;
    const int NBUK = (N + (1 << BSHIFT) - 1) >> BSHIFT;   // 391 @ N=100k (<= 512)
    const int nblk = (E + CHUNK - 1) / CHUNK;             // 586 @ E=1.2M

    // ws: flags | bukTot | bukOff | rowptr[N+1] | recs[E] | esorted[E] | xb | h
    // blockHist overlays xb (dead before k_cast writes xb).
    char* base = (char*)d_ws;
    size_t off = 0;
    auto alloc = [&](size_t bytes) { size_t o = off; off = (off + bytes + 255) & ~(size_t)255; return o; };
    int* flags   = (int*)(base + alloc(256));
    int* bukTot  = (int*)(base + alloc((size_t)NBUK * 4));
    int* bukOff  = (int*)(base + alloc((size_t)(NBUK + 1) * 4));
    int* rowptr  = (int*)(base + alloc((size_t)(N + 1) * 4));
    unsigned int* recs = (unsigned int*)(base + alloc((size_t)E * 4));
    int* esorted = (int*)(base + alloc((size_t)E * 4));
    unsigned short* xb = (unsigned short*)(base + alloc((size_t)N * 64 * 2));
    unsigned short* h  = (unsigned short*)(base + alloc((size_t)N * 64 * 2));
    (void)ws_size;

    int* blockHist = (int*)xb;     // [NBUK][nblk], dead after k_part

    const int B = 256;
    int nd = 2 * E; if (nd > 2048) nd = 2048;

    k_detect<<<1, 256, 0, stream>>>(ei, nd, (const unsigned int*)x, 512, flags);
    k_bcount<<<nblk, B, 0, stream>>>(ei, flags, blockHist, E, NBUK, nblk);
    k_rowscan<<<NBUK, B, 0, stream>>>(blockHist, bukTot, nblk);
    k_toto<<<1, 512, 0, stream>>>(bukTot, bukOff, rowptr, NBUK, E, N);
    k_part<<<nblk, B, 0, stream>>>(ei, flags, blockHist, bukOff, recs, E, NBUK, nblk);
    k_cast<<<(N * 8 + B - 1) / B, B, 0, stream>>>(x, xb, N * 8, flags);
    k_csr<<<NBUK, B, 0, stream>>>(recs, bukOff, rowptr, esorted, N);

    const int ntile = (N + 127) / 128;
    // h = relu( mean_nbr(xb)@W1l + xb@W1r + b1 )
    k_fused<64, true, false><<<ntile, 512, 0, stream>>>(xb, rowptr, esorted,
                                                        W1l, W1r, b1, h, N, flags);
    // out = mean_nbr(h)@W2l + h@W2r + b2
    k_fused<32, false, true><<<ntile, 512, 0, stream>>>(h, rowptr, esorted,
                                                        W2l, W2r, b2, d_out, N, flags);
}

// Round 11
// 236.887 us; speedup vs baseline: 8.3176x; 8.3176x over previous
//
#include <hip/hip_runtime.h>

// ---------- bf16 helpers (bit-level, RNE) ----------
__device__ __forceinline__ float bf2f(unsigned short u) {
    union { unsigned int i; float f; } v;
    v.i = ((unsigned int)u) << 16;
    return v.f;
}
__device__ __forceinline__ unsigned short f2bf(float f) {
    union { float f; unsigned int u; } v;
    v.f = f;
    unsigned int u = v.u;
    u += 0x7FFFu + ((u >> 16) & 1u);   // round-to-nearest-even
    return (unsigned short)(u >> 16);
}
__device__ __forceinline__ float loadElem(const void* p, size_t i, int isb) {
    return isb ? bf2f(((const unsigned short*)p)[i]) : ((const float*)p)[i];
}
__device__ __forceinline__ void fma4(float4& a, float s, const float4& w) {
    a.x += s * w.x; a.y += s * w.y; a.z += s * w.z; a.w += s * w.w;
}
__device__ __forceinline__ float bflo(unsigned int u) {
    union { unsigned int i; float f; } v; v.i = u << 16; return v.f;
}
__device__ __forceinline__ float bfhi(unsigned int u) {
    union { unsigned int i; float f; } v; v.i = u & 0xFFFF0000u; return v.f;
}

#define CHUNK 4096            // edges per partition block (r7/r9 proven)
#define BSHIFT 8              // 256 nodes per sort bucket (r7 proven)

// ---------- runtime dtype detection (proven r3-r10) ----------
__global__ void k_detect(const int* __restrict__ ei, int newords,
                         const unsigned int* __restrict__ xw, int nxw,
                         int* __restrict__ flags) {
    __shared__ int aOr;
    __shared__ int plaus;
    if (threadIdx.x == 0) { aOr = 0; plaus = 0; }
    __syncthreads();
    int v = 0;
    for (int i = 1 + 2 * (int)threadIdx.x; i < newords; i += 512) v |= ei[i];
    int pl = 0;
    for (int i = threadIdx.x; i < nxw; i += 256) {
        unsigned short lo = (unsigned short)(xw[i] & 0xFFFFu);
        float a = fabsf(bf2f(lo));
        if (a > 1e-5f && a < 100.0f) pl++;
    }
    atomicOr(&aOr, v);
    atomicAdd(&plaus, pl);
    __syncthreads();
    if (threadIdx.x == 0) {
        flags[0] = (aOr == 0) ? 1 : 0;
        flags[1] = (2 * plaus >= nxw) ? 1 : 0;
    }
}

// ---------- cast x -> bf16 (copy-through if already bf16) ----------
__global__ void k_cast(const void* __restrict__ x, unsigned short* __restrict__ xb,
                       int n8, const int* __restrict__ flags) {
    int i = blockIdx.x * blockDim.x + threadIdx.x;
    if (i >= n8) return;
    if (flags[1]) {
        ((uint4*)xb)[i] = ((const uint4*)x)[i];
    } else {
        const float4* xf = (const float4*)x;
        float4 a = xf[2 * i], b = xf[2 * i + 1];
        ushort4 lo = { f2bf(a.x), f2bf(a.y), f2bf(a.z), f2bf(a.w) };
        ushort4 hi = { f2bf(b.x), f2bf(b.y), f2bf(b.z), f2bf(b.w) };
        ((ushort4*)xb)[2 * i] = lo;
        ((ushort4*)xb)[2 * i + 1] = hi;
    }
}

// ---------- CSR build: counting sort with parallel scans (r7/r9 verbatim) ----------
__global__ __launch_bounds__(256) void k_bcount(
        const int* __restrict__ ei, const int* __restrict__ flags,
        int* __restrict__ blockHist, int E, int NBUK, int nblk) {
    __shared__ int hist[512];
    int t = threadIdx.x;
    for (int i = t; i < NBUK; i += 256) hist[i] = 0;
    __syncthreads();
    int q = flags[0];
    int e0 = blockIdx.x * CHUNK, e1 = min(E, e0 + CHUNK);
    for (int e = e0 + t; e < e1; e += 256) {
        int dst = ei[((size_t)(E + e)) << q];
        atomicAdd(&hist[dst >> BSHIFT], 1);
    }
    __syncthreads();
    for (int i = t; i < NBUK; i += 256)
        blockHist[(size_t)i * nblk + blockIdx.x] = hist[i];
}

__global__ __launch_bounds__(256) void k_rowscan(
        int* __restrict__ blockHist, int* __restrict__ bukTot, int nblk) {
    __shared__ int sh[256];
    int t = threadIdx.x;
    int* row = blockHist + (size_t)blockIdx.x * nblk;
    int carry = 0;
    for (int base = 0; base < nblk; base += 256) {
        int i = base + t;
        int v = (i < nblk) ? row[i] : 0;
        sh[t] = v;
        __syncthreads();
        for (int off = 1; off < 256; off <<= 1) {
            int u = (t >= off) ? sh[t - off] : 0;
            __syncthreads();
            sh[t] += u;
            __syncthreads();
        }
        if (i < nblk) row[i] = carry + sh[t] - v;
        int tot = sh[255];
        __syncthreads();
        carry += tot;
    }
    if (t == 0) bukTot[blockIdx.x] = carry;
}

__global__ __launch_bounds__(512) void k_toto(
        const int* __restrict__ bukTot, int* __restrict__ bukOff,
        int* __restrict__ rowptr, int NBUK, int E, int N) {
    __shared__ int sh[512];
    int t = threadIdx.x;
    int v = (t < NBUK) ? bukTot[t] : 0;
    sh[t] = v;
    __syncthreads();
    for (int off = 1; off < 512; off <<= 1) {
        int u = (t >= off) ? sh[t - off] : 0;
        __syncthreads();
        sh[t] += u;
        __syncthreads();
    }
    if (t < NBUK) bukOff[t] = sh[t] - v;
    if (t == 0) { bukOff[NBUK] = E; rowptr[N] = E; }
}

__global__ __launch_bounds__(256) void k_part(
        const int* __restrict__ ei, const int* __restrict__ flags,
        const int* __restrict__ blockHist, const int* __restrict__ bukOff,
        unsigned int* __restrict__ recs, int E, int NBUK, int nblk) {
    __shared__ int cur[512];
    int t = threadIdx.x;
    for (int i = t; i < NBUK; i += 256)
        cur[i] = blockHist[(size_t)i * nblk + blockIdx.x] + bukOff[i];
    __syncthreads();
    int q = flags[0];
    int e0 = blockIdx.x * CHUNK, e1 = min(E, e0 + CHUNK);
    for (int e = e0 + t; e < e1; e += 256) {
        int dst = ei[((size_t)(E + e)) << q];
        int src = ei[((size_t)e) << q];
        int pos = atomicAdd(&cur[dst >> BSHIFT], 1);
        recs[pos] = ((unsigned int)src << BSHIFT) | (unsigned int)(dst & ((1 << BSHIFT) - 1));
    }
}

__global__ __launch_bounds__(256) void k_csr(
        const unsigned int* __restrict__ recs, const int* __restrict__ bukOff,
        int* __restrict__ rowptr, int* __restrict__ esorted, int N) {
    __shared__ int degLoc[256];
    __shared__ int offLoc[256];
    __shared__ int wcur[256];
    int t = threadIdx.x;
    int node0 = blockIdx.x << BSHIFT;
    int r0 = bukOff[blockIdx.x], r1 = bukOff[blockIdx.x + 1];
    degLoc[t] = 0;
    __syncthreads();
    for (int i = r0 + t; i < r1; i += 256)
        atomicAdd(&degLoc[recs[i] & 255], 1);
    __syncthreads();
    int v = degLoc[t];
    offLoc[t] = v;
    __syncthreads();
    for (int off = 1; off < 256; off <<= 1) {
        int u = (t >= off) ? offLoc[t - off] : 0;
        __syncthreads();
        offLoc[t] += u;
        __syncthreads();
    }
    int excl = offLoc[t] - v;
    int node = node0 + t;
    if (node < N) rowptr[node] = r0 + excl;
    wcur[t] = r0 + excl;
    __syncthreads();
    for (int i = r0 + t; i < r1; i += 256) {
        unsigned int rec = recs[i];
        int pos = atomicAdd(&wcur[rec & 255], 1);
        esorted[pos] = (int)(rec >> BSHIFT);
    }
}

// ---------- fused layer (r9 structure; ONLY change: weights staged as bf16) ----------
// One block = 64 nodes, 256 threads. Phase 1: 16-lane-group register gather ->
// amBuf (f32). Phase 2: acc = am @ Wl. Restage (own rows; Wr). Phase 3:
// acc += own @ Wr. Epilogue +bias (+relu).
// LDS: amBuf 17.4K + wS16 (CHOUT*128 B) + Bs -> 25.7K @ CHOUT=64 => 6 blk/CU (was 4)
template<int CHOUT, bool RELU, bool FINAL>
__global__ __launch_bounds__(256) void k_fused(
        const unsigned short* __restrict__ feat,   // [N,64] bf16: xb (L1) or h (L2)
        const int* __restrict__ rowptr,
        const int* __restrict__ esorted,
        const void* __restrict__ Wl,               // [64,CHOUT]
        const void* __restrict__ Wr,               // [64,CHOUT]
        const void* __restrict__ bias,             // [CHOUT]
        void* __restrict__ outp,                   // [N,CHOUT]
        int N, const int* __restrict__ flags) {
    constexpr int SA = 68;                         // f32 stride, 16B-aligned float4
    __shared__ float amBuf[64 * SA];
    __shared__ unsigned short wS16[64 * CHOUT];    // bf16 weights (was f32 in r9)
    __shared__ float Bs[CHOUT];

    int t = threadIdx.x;
    int isb = flags[1];
    int node0 = blockIdx.x << 6;

    // stage Wl as bf16: raw copy if already bf16, else f32 -> RNE bf16
    if (isb) {
        for (int i = t; i < (64 * CHOUT) / 8; i += 256)
            ((uint4*)wS16)[i] = ((const uint4*)Wl)[i];
    } else {
        for (int i = t; i < 64 * CHOUT; i += 256)
            wS16[i] = f2bf(((const float*)Wl)[i]);
    }
    if (t < CHOUT) Bs[t] = loadElem(bias, t, isb);

    // ---- phase 1: gather mean of neighbor rows -> amBuf[nl][k] (r9 verbatim) ----
    {
        int g = t >> 4, l = t & 15;
        int gb = (t & 63) & ~15;                   // group base lane within wave
#pragma unroll
        for (int jj = 0; jj < 4; ++jj) {
            int nl = g + 16 * jj;
            int node = node0 + nl;
            float ax = 0.f, ay = 0.f, az = 0.f, aw = 0.f;
            float inv = 0.f;
            if (node < N) {
                int beg = rowptr[node], end = rowptr[node + 1];
                int d = end - beg;
                if (d > 0) {
                    inv = 1.0f / (float)d;
                    for (int bs = beg; bs < end; bs += 16) {
                        int cnt = min(end - bs, 16);
                        int idx = esorted[min(bs + l, end - 1)];
                        int dd = 0;
                        for (; dd + 4 <= cnt; dd += 4) {
                            int s0 = __shfl(idx, gb + dd + 0, 64);
                            int s1 = __shfl(idx, gb + dd + 1, 64);
                            int s2 = __shfl(idx, gb + dd + 2, 64);
                            int s3 = __shfl(idx, gb + dd + 3, 64);
                            ushort4 u0 = *(const ushort4*)(feat + (size_t)s0 * 64 + 4 * l);
                            ushort4 u1 = *(const ushort4*)(feat + (size_t)s1 * 64 + 4 * l);
                            ushort4 u2 = *(const ushort4*)(feat + (size_t)s2 * 64 + 4 * l);
                            ushort4 u3 = *(const ushort4*)(feat + (size_t)s3 * 64 + 4 * l);
                            ax += bf2f(u0.x) + bf2f(u1.x) + bf2f(u2.x) + bf2f(u3.x);
                            ay += bf2f(u0.y) + bf2f(u1.y) + bf2f(u2.y) + bf2f(u3.y);
                            az += bf2f(u0.z) + bf2f(u1.z) + bf2f(u2.z) + bf2f(u3.z);
                            aw += bf2f(u0.w) + bf2f(u1.w) + bf2f(u2.w) + bf2f(u3.w);
                        }
                        for (; dd < cnt; ++dd) {
                            int s = __shfl(idx, gb + dd, 64);
                            ushort4 u = *(const ushort4*)(feat + (size_t)s * 64 + 4 * l);
                            ax += bf2f(u.x); ay += bf2f(u.y);
                            az += bf2f(u.z); aw += bf2f(u.w);
                        }
                    }
                }
            }
            *(float4*)&amBuf[nl * SA + 4 * l] =
                make_float4(ax * inv, ay * inv, az * inv, aw * inv);
        }
    }
    __syncthreads();

    // ---- phase 2: acc = am @ Wl ----
    constexpr int CQ = CHOUT / 4;                  // 16 or 8
    constexpr int NPT = CHOUT / 16;                // 4 or 2 nodes per thread
    int cq = t % CQ, nq = t / CQ;
    float4 acc[NPT];
#pragma unroll
    for (int j = 0; j < NPT; ++j) acc[j] = make_float4(0.f, 0.f, 0.f, 0.f);

#pragma unroll 8
    for (int k = 0; k < 64; ++k) {
        uint2 wu = *(const uint2*)&wS16[k * CHOUT + 4 * cq];
        float4 w = make_float4(bflo(wu.x), bfhi(wu.x), bflo(wu.y), bfhi(wu.y));
#pragma unroll
        for (int j = 0; j < NPT; ++j)
            fma4(acc[j], amBuf[(nq * NPT + j) * SA + k], w);
    }
    __syncthreads();

    // ---- restage: own rows -> amBuf, Wr -> wS16 ----
    for (int i = t; i < 64 * 8; i += 256) {
        int nl = i >> 3, k0 = (i & 7) << 3;
        int gn = node0 + nl;
        float v[8];
        if (gn < N) {
            uint4 u = *(const uint4*)(feat + (size_t)gn * 64 + k0);
            v[0] = bflo(u.x); v[1] = bfhi(u.x);
            v[2] = bflo(u.y); v[3] = bfhi(u.y);
            v[4] = bflo(u.z); v[5] = bfhi(u.z);
            v[6] = bflo(u.w); v[7] = bfhi(u.w);
        } else {
#pragma unroll
            for (int j = 0; j < 8; ++j) v[j] = 0.f;
        }
#pragma unroll
        for (int j = 0; j < 8; ++j) amBuf[nl * SA + k0 + j] = v[j];
    }
    if (isb) {
        for (int i = t; i < (64 * CHOUT) / 8; i += 256)
            ((uint4*)wS16)[i] = ((const uint4*)Wr)[i];
    } else {
        for (int i = t; i < 64 * CHOUT; i += 256)
            wS16[i] = f2bf(((const float*)Wr)[i]);
    }
    __syncthreads();

    // ---- phase 3: acc += own @ Wr ----
#pragma unroll 8
    for (int k = 0; k < 64; ++k) {
        uint2 wu = *(const uint2*)&wS16[k * CHOUT + 4 * cq];
        float4 w = make_float4(bflo(wu.x), bfhi(wu.x), bflo(wu.y), bfhi(wu.y));
#pragma unroll
        for (int j = 0; j < NPT; ++j)
            fma4(acc[j], amBuf[(nq * NPT + j) * SA + k], w);
    }

    // ---- epilogue ----
    float4 bv = *(const float4*)&Bs[4 * cq];
#pragma unroll
    for (int j = 0; j < NPT; ++j) {
        int nl = nq * NPT + j;
        int node = node0 + nl;
        if (node >= N) continue;
        float4 r = acc[j];
        r.x += bv.x; r.y += bv.y; r.z += bv.z; r.w += bv.w;
        if (RELU) {
            r.x = fmaxf(r.x, 0.f); r.y = fmaxf(r.y, 0.f);
            r.z = fmaxf(r.z, 0.f); r.w = fmaxf(r.w, 0.f);
        }
        if (FINAL && !isb) {
            *(float4*)((float*)outp + (size_t)node * CHOUT + 4 * cq) = r;
        } else {
            ushort4 o = { f2bf(r.x), f2bf(r.y), f2bf(r.z), f2bf(r.w) };
            *(ushort4*)((unsigned short*)outp + (size_t)node * CHOUT + 4 * cq) = o;
        }
    }
}

extern "C" void kernel_launch(void* const* d_in, const int* in_sizes, int n_in,
                              void* d_out, int out_size, void* d_ws, size_t ws_size,
                              hipStream_t stream) {
    const void* x   = d_in[0];
    const int*  ei  = (const int*)d_in[1];
    const void* W1l = d_in[2];
    const void* W1r = d_in[3];
    const void* b1  = d_in[4];
    const void* W2l = d_in[5];
    const void* W2r = d_in[6];
    const void* b2  = d_in[7];

    const int N = in_sizes[0] / 64;
    const int E = in_sizes[1] / 2;
    const int NBUK = (N + (1 << BSHIFT) - 1) >> BSHIFT;   // 391 @ N=100k (<= 512)
    const int nblk = (E + CHUNK - 1) / CHUNK;             // 293 @ E=1.2M

    // ws: flags | bukTot | bukOff | rowptr[N+1] | recs[E] | esorted[E] | xb | h
    // blockHist overlays xb (dead before k_cast writes xb).
    char* base = (char*)d_ws;
    size_t off = 0;
    auto alloc = [&](size_t bytes) { size_t o = off; off = (off + bytes + 255) & ~(size_t)255; return o; };
    int* flags   = (int*)(base + alloc(256));
    int* bukTot  = (int*)(base + alloc((size_t)NBUK * 4));
    int* bukOff  = (int*)(base + alloc((size_t)(NBUK + 1) * 4));
    int* rowptr  = (int*)(base + alloc((size_t)(N + 1) * 4));
    unsigned int* recs = (unsigned int*)(base + alloc((size_t)E * 4));
    int* esorted = (int*)(base + alloc((size_t)E * 4));
    unsigned short* xb = (unsigned short*)(base + alloc((size_t)N * 64 * 2));
    unsigned short* h  = (unsigned short*)(base + alloc((size_t)N * 64 * 2));
    (void)ws_size;

    int* blockHist = (int*)xb;     // [NBUK][nblk], dead after k_part

    const int B = 256;
    int nd = 2 * E; if (nd > 2048) nd = 2048;

    k_detect<<<1, 256, 0, stream>>>(ei, nd, (const unsigned int*)x, 512, flags);
    k_bcount<<<nblk, B, 0, stream>>>(ei, flags, blockHist, E, NBUK, nblk);
    k_rowscan<<<NBUK, B, 0, stream>>>(blockHist, bukTot, nblk);
    k_toto<<<1, 512, 0, stream>>>(bukTot, bukOff, rowptr, NBUK, E, N);
    k_part<<<nblk, B, 0, stream>>>(ei, flags, blockHist, bukOff, recs, E, NBUK, nblk);
    k_cast<<<(N * 8 + B - 1) / B, B, 0, stream>>>(x, xb, N * 8, flags);
    k_csr<<<NBUK, B, 0, stream>>>(recs, bukOff, rowptr, esorted, N);

    const int ntile = (N + 63) / 64;
    // h = relu( mean_nbr(xb)@W1l + xb@W1r + b1 )
    k_fused<64, true, false><<<ntile, B, 0, stream>>>(xb, rowptr, esorted,
                                                      W1l, W1r, b1, h, N, flags);
    // out = mean_nbr(h)@W2l + h@W2r + b2
    k_fused<32, false, true><<<ntile, B, 0, stream>>>(h, rowptr, esorted,
                                                      W2l, W2r, b2, d_out, N, flags);
}